// Round 7
// baseline (132.745 us; speedup 1.0000x reference)
//
#include <hip/hip_runtime.h>

constexpr int BS = 32;
constexpr int D  = 2048;
constexpr float P = 0.5f;

constexpr int TPB = 256;            // threads per block
constexpr int KC  = 64;             // k-chunks
constexpr int KCH = D / KC;         // 32 k rows per chunk
constexpr int DV  = D / 4;          // float4 per row (512)
constexpr int HALF = DV / 2;        // 256 float4 = half row

typedef float floatx4 __attribute__((ext_vector_type(4)));

// Each block covers a FULL 8KB row per k-step via two 1KB-coalesced
// half-row streams per wave (lane addresses contiguous within each load).
// unroll 4 -> 8 outstanding u_w loads/wave = 8KB in flight (4x the R1
// structure) to test the MLP/latency hypothesis at constant traffic.
__global__ __launch_bounds__(TPB, 4) void dropconnect_kernel(
    const float* __restrict__ x,      // (BS, D)
    const float* __restrict__ weight, // (D, D)   axes (k, n)
    const float* __restrict__ bias,   // (D,)
    const float* __restrict__ u_w,    // (BS, D, D) axes (b, k, n)
    const float* __restrict__ u_b,    // (BS, D)
    float* __restrict__ out)          // (BS, D), pre-zeroed
{
    const int kc  = blockIdx.x;   // 0..63; flat%8 = kc%8 -> same-XCD weight tile
    const int b   = blockIdx.z;
    const int tid = threadIdx.x;

    const int k0 = kc * KCH;

    __shared__ float xs[KCH];
    if (tid < KCH) xs[tid] = x[b * D + k0 + tid];
    __syncthreads();

    const floatx4* uw4 = reinterpret_cast<const floatx4*>(u_w);
    const floatx4* w4  = reinterpret_cast<const floatx4*>(weight);

    float accA[4] = {}, accB[4] = {};

    size_t iu = ((size_t)b * D + (size_t)k0) * DV + tid;  // half A
    size_t iw = (size_t)k0 * DV + tid;

#pragma unroll 4
    for (int kk = 0; kk < KCH; ++kk) {
        const float xv = xs[kk];
        const floatx4 uA = uw4[iu];
        const floatx4 uB = uw4[iu + HALF];
        const floatx4 wA = w4[iw];
        const floatx4 wB = w4[iw + HALF];
        accA[0] += (uA.x <= P) ? xv * wA.x : 0.f;
        accA[1] += (uA.y <= P) ? xv * wA.y : 0.f;
        accA[2] += (uA.z <= P) ? xv * wA.z : 0.f;
        accA[3] += (uA.w <= P) ? xv * wA.w : 0.f;
        accB[0] += (uB.x <= P) ? xv * wB.x : 0.f;
        accB[1] += (uB.y <= P) ? xv * wB.y : 0.f;
        accB[2] += (uB.z <= P) ? xv * wB.z : 0.f;
        accB[3] += (uB.w <= P) ? xv * wB.w : 0.f;
        iu += DV;
        iw += DV;
    }

    const int nA = tid * 4;            // first owned column (half A)
    const int nB = 4 * HALF + tid * 4; // half B (n + 1024)

    if (kc == 0) {
        const floatx4 ubA = reinterpret_cast<const floatx4*>(u_b)[(b * D + nA) >> 2];
        const floatx4 ubB = reinterpret_cast<const floatx4*>(u_b)[(b * D + nB) >> 2];
        const floatx4 bvA = reinterpret_cast<const floatx4*>(bias)[nA >> 2];
        const floatx4 bvB = reinterpret_cast<const floatx4*>(bias)[nB >> 2];
        accA[0] += (ubA.x <= P) ? bvA.x : 0.f;
        accA[1] += (ubA.y <= P) ? bvA.y : 0.f;
        accA[2] += (ubA.z <= P) ? bvA.z : 0.f;
        accA[3] += (ubA.w <= P) ? bvA.w : 0.f;
        accB[0] += (ubB.x <= P) ? bvB.x : 0.f;
        accB[1] += (ubB.y <= P) ? bvB.y : 0.f;
        accB[2] += (ubB.z <= P) ? bvB.z : 0.f;
        accB[3] += (ubB.w <= P) ? bvB.w : 0.f;
    }

    float* oA = out + (size_t)b * D + nA;
    float* oB = out + (size_t)b * D + nB;
    atomicAdd(oA + 0, accA[0]);
    atomicAdd(oA + 1, accA[1]);
    atomicAdd(oA + 2, accA[2]);
    atomicAdd(oA + 3, accA[3]);
    atomicAdd(oB + 0, accB[0]);
    atomicAdd(oB + 1, accB[1]);
    atomicAdd(oB + 2, accB[2]);
    atomicAdd(oB + 3, accB[3]);
}

extern "C" void kernel_launch(void* const* d_in, const int* in_sizes, int n_in,
                              void* d_out, int out_size, void* d_ws, size_t ws_size,
                              hipStream_t stream) {
    const float* x      = (const float*)d_in[0];
    const float* weight = (const float*)d_in[1];
    const float* bias   = (const float*)d_in[2];
    const float* u_w    = (const float*)d_in[3];
    const float* u_b    = (const float*)d_in[4];
    float* out = (float*)d_out;

    // out is poisoned (0xAA) before timing; atomic path needs zeros each call.
    (void)hipMemsetAsync(out, 0, (size_t)out_size * sizeof(float), stream);

    dim3 grid(KC, 1, BS);
    dropconnect_kernel<<<grid, TPB, 0, stream>>>(x, weight, bias, u_w, u_b, out);
}

// Round 8
// 116.277 us; speedup vs baseline: 1.1416x; 1.1416x over previous
//
#include <hip/hip_runtime.h>

constexpr int BS = 32;
constexpr int D  = 2048;
constexpr float P = 0.5f;

constexpr int TPB = 256;            // threads per block
constexpr int NPT = 4;              // n-elements per thread (float4)
constexpr int NB  = D / (TPB*NPT);  // 2 n-blocks
constexpr int KC  = 32;             // k-chunks
constexpr int KCH = D / KC;         // 64 k rows per chunk
constexpr int DV  = D / 4;          // float4 per row

typedef float floatx4 __attribute__((ext_vector_type(4)));

// Best-known structure (R1/R4/R6 all 116.4-116.8 us, +-0.2%):
//  - one coalesced u_w float4 stream per thread, stride 8KB per k-step
//  - weight L2-resident via implicit same-XCD tile affinity (f%8 = kc%8)
//  - block-uniform x staged in LDS
//  - atomic output accumulation (proven free vs ws+reduce path)
// Proven-neutral/negative variants: BPB reuse (-36us), 2-stream MLP (-16us),
// nontemporal (-14us), occupancy x2 (0), ws+reduce (0).
__global__ __launch_bounds__(TPB, 8) void dropconnect_kernel(
    const float* __restrict__ x,      // (BS, D)
    const float* __restrict__ weight, // (D, D)   axes (k, n)
    const float* __restrict__ bias,   // (D,)
    const float* __restrict__ u_w,    // (BS, D, D) axes (b, k, n)
    const float* __restrict__ u_b,    // (BS, D)
    float* __restrict__ out)          // (BS, D), pre-zeroed
{
    const int kc  = blockIdx.x;   // f%8 = kc%8 -> same-XCD weight-tile affinity
    const int nb  = blockIdx.y;
    const int b   = blockIdx.z;
    const int tid = threadIdx.x;

    const int n0 = nb * (TPB * NPT) + tid * NPT;
    const int k0 = kc * KCH;

    __shared__ float xs[KCH];
    if (tid < KCH) xs[tid] = x[b * D + k0 + tid];
    __syncthreads();

    const floatx4* uw4 = reinterpret_cast<const floatx4*>(u_w);
    const floatx4* w4  = reinterpret_cast<const floatx4*>(weight);

    float acc0 = 0.f, acc1 = 0.f, acc2 = 0.f, acc3 = 0.f;

    size_t iu = ((size_t)b * D + (size_t)k0) * DV + (n0 >> 2);
    size_t iw = (size_t)k0 * DV + (n0 >> 2);

#pragma unroll 2
    for (int kk = 0; kk < KCH; ++kk) {
        const float xv = xs[kk];
        const floatx4 u = uw4[iu];
        const floatx4 w = w4[iw];
        acc0 += (u.x <= P) ? xv * w.x : 0.f;
        acc1 += (u.y <= P) ? xv * w.y : 0.f;
        acc2 += (u.z <= P) ? xv * w.z : 0.f;
        acc3 += (u.w <= P) ? xv * w.w : 0.f;
        iu += DV;
        iw += DV;
    }

    if (kc == 0) {
        const floatx4 ub = reinterpret_cast<const floatx4*>(u_b)[(b * D + n0) >> 2];
        const floatx4 bv = reinterpret_cast<const floatx4*>(bias)[n0 >> 2];
        acc0 += (ub.x <= P) ? bv.x : 0.f;
        acc1 += (ub.y <= P) ? bv.y : 0.f;
        acc2 += (ub.z <= P) ? bv.z : 0.f;
        acc3 += (ub.w <= P) ? bv.w : 0.f;
    }

    float* o = out + (size_t)b * D + n0;
    atomicAdd(o + 0, acc0);
    atomicAdd(o + 1, acc1);
    atomicAdd(o + 2, acc2);
    atomicAdd(o + 3, acc3);
}

extern "C" void kernel_launch(void* const* d_in, const int* in_sizes, int n_in,
                              void* d_out, int out_size, void* d_ws, size_t ws_size,
                              hipStream_t stream) {
    const float* x      = (const float*)d_in[0];
    const float* weight = (const float*)d_in[1];
    const float* bias   = (const float*)d_in[2];
    const float* u_w    = (const float*)d_in[3];
    const float* u_b    = (const float*)d_in[4];
    float* out = (float*)d_out;

    // out is poisoned (0xAA) before timing; atomic path needs zeros each call.
    (void)hipMemsetAsync(out, 0, (size_t)out_size * sizeof(float), stream);

    dim3 grid(KC, NB, BS);
    dropconnect_kernel<<<grid, TPB, 0, stream>>>(x, weight, bias, u_w, u_b, out);
}